// Round 6
// baseline (402.494 us; speedup 1.0000x reference)
//
#include <hip/hip_runtime.h>
#include <hip/hip_bf16.h>
#include <math.h>

// ---------- types ----------
typedef __attribute__((ext_vector_type(8))) short s8vec;     // 8 x bf16 bits (4 VGPRs)
typedef __attribute__((ext_vector_type(16))) float f32x16;   // 32x32 MFMA C/D
typedef __attribute__((ext_vector_type(4))) unsigned short us4;
typedef __attribute__((ext_vector_type(8))) unsigned short us8;

__device__ __forceinline__ unsigned short f2bf(float f) {
  unsigned u = __float_as_uint(f);
  u = (u + 0x7fffu + ((u >> 16) & 1u)) >> 16;   // RNE
  return (unsigned short)u;
}
__device__ __forceinline__ float bf2f(unsigned short u) {
  return __uint_as_float(((unsigned)u) << 16);
}

// fast gelu: t * sigmoid(1.5957691t + 0.07135481t^3); |err vs erf-gelu| < 3e-3
__device__ __forceinline__ float fast_gelu(float t) {
  float t2 = t * t;
  float u = t * (1.59576912f + 0.07135481f * t2);
  float e = __expf(-u);
  return t * __frcp_rn(1.0f + e);
}

// async global->LDS, 16B per lane. LDS dest = WAVE-UNIFORM base (+ lane*16 by HW).
__device__ __forceinline__ void async_ld16(const unsigned short* g, unsigned short* l) {
  __builtin_amdgcn_global_load_lds(
      (__attribute__((address_space(1))) void*)g,
      (__attribute__((address_space(3))) void*)l, 16, 0, 0);
}

// ============================================================================
// 128x128 NT GEMM: C[M,N] = A[M,K] * Bt[N,K]^T   — 2 blocks/CU edition
//
// Rounds 0-5: six schedule variants on 256-tile/1-block-per-CU all plateau at
// ~90-105 us (MfmaUtil ~31%). Counter model: per-K-tile wall 6780 cyc vs MFMA
// 2068 + LDS ~2800 — the slack is CU-wide barrier coupling with no co-resident
// block to fill it.  This round: 128x128 tile, 4 waves (256 thr), 64 KiB LDS
// -> 2 independent blocks/CU; each SIMD runs 2 waves from DIFFERENT blocks
// (decoupled barriers) so one block's MFMA covers the other's stalls.
//
// Per K-tile (2 windows; proven round-4 machinery, stripes halved):
//  WA: read B(8)+A-mf0(4) [batch1], read-ahead A-mf1(4) [batch2];
//      stage A-stripes{1,3}(t+1, other buf);
//      lgkm(4) [batch1 done; batch2 in flight; DS retires in-order]
//      setprio1; 8 MFMA (mf0) ; setprio0 ; s_barrier
//  WB: stage B0-3(t+2)+A{0,2}(t+2) (this buf);
//      lgkm(0); setprio1; 8 MFMA (mf1); setprio0;
//      vmcnt(6) (tail: 0) ; s_barrier
// Stage ledger: A{1,3}(t+1) -> other buf (its t-1 data was read by WA(t-1)
// batch2, completed at WB(t-1) lgkm(0), barrier after).  B(t+2)/A{0,2}(t+2)
// -> this buf (read in batch1, completed at lgkm(4) before WA-end barrier).
// Queue at WB(t)-end: [WB(t-1): 6 of t+1][WA(t): 2 of t+1][WB(t): 6 of t+2]
// = 14 -> vmcnt(6) drains all 8 of t+1.  One vmem fence per tile.
//
// T1 XCD-aware bijective remap (nwg%8==0, gx/gy pow2 at all sites).
// LDS swizzle (0 measured conflict cycles, rounds 0-4): 16B chunk c of row r
// at c ^ (r&7) ^ ((r>>3)&3); global source pre-swizzled, LDS linear; stage
// chunk (tid&7)^((tid>>3)&7)^((tid>>6)&3) is stripe-invariant.
// 32x32x16 frags; C/D: col=lane&31, row=(reg&3)+8*(reg>>2)+4*(lane>>5).
// EPI: 0 = out_bf16 = acc*scale; 1 = out_f32 = acc+res;
//      2 = out_bf16 = gelu(acc+bias); 3 = out_f32 = acc+bias+res
// ============================================================================

#define STA(q, tk, bofs)                                                    \
  async_ld16(srcA0 + (size_t)(q) * 32 * K + ((size_t)(tk) << 6),            \
             &As[(bofs) + ((q) << 11) + ldsW])
#define STB(j, tk, bofs)                                                    \
  async_ld16(srcB0 + (size_t)(j) * 32 * K + ((size_t)(tk) << 6),            \
             &Bs[(bofs) + ((j) << 11) + ldsW])

#define SB0() __builtin_amdgcn_sched_barrier(0)

template <int EPI>
__global__ __launch_bounds__(256, 2) void gemm128(
    const unsigned short* __restrict__ A, const unsigned short* __restrict__ B,
    float* __restrict__ outF, unsigned short* __restrict__ outB,
    const float* __restrict__ bias, const float* __restrict__ res,
    int M, int N, int K,
    long long bA, long long bB, long long bO, long long bR, float scale)
{
  constexpr int ABUF = 128 * 64;   // 16 KiB per buffer
  __shared__ __align__(16) unsigned short As[2 * ABUF];   // 32 KiB
  __shared__ __align__(16) unsigned short Bs[2 * ABUF];   // 32 KiB

  (void)M;
  const int tid = threadIdx.x;
  const int w = tid >> 6;          // wave 0..3
  const int l = tid & 63;

  // ---- T1: XCD-aware bijective remap (nwg % 8 == 0, gx/gy pow2) ----
  const unsigned gx = gridDim.x, gy = gridDim.y;
  unsigned lin = blockIdx.x + gx * (blockIdx.y + gy * blockIdx.z);
  const unsigned nwg = gx * gy * gridDim.z;
  lin = (lin & 7u) * (nwg >> 3) + (lin >> 3);
  const unsigned bx = lin & (gx - 1u);
  const unsigned tmp = lin >> __builtin_ctz(gx);
  const unsigned by = tmp & (gy - 1u);
  const unsigned bz = tmp >> __builtin_ctz(gy);

  const int z = (int)bz;
  A += (size_t)z * bA;
  B += (size_t)z * bB;
  const size_t tileM = (size_t)by * 128;
  const size_t tileN = (size_t)bx * 128;

  // ---- staging bases (global pre-swizzled, LDS linear) ----
  // stripe = 32 rows x 64 K = 4 KiB = one async_ld16 per thread.
  // thread: row-in-stripe = tid>>3, chunk = (tid&7)^((tid>>3)&7)^((tid>>6)&3)
  const int cS = (tid & 7) ^ ((tid >> 3) & 7) ^ ((tid >> 6) & 3);
  const unsigned short* srcA0 = A + (tileM + (tid >> 3)) * (size_t)K + (cS << 3);
  const unsigned short* srcB0 = B + (tileN + (tid >> 3)) * (size_t)K + (cS << 3);
  const int ldsW = w << 9;         // wave-uniform LDS offset within stripe

  // ---- compute-side fragment addressing (proven 0-conflict pattern) ----
  const int wm = w >> 1;           // wave M origin / 64
  const int wn = w & 1;            // wave N origin / 64
  const int fr = l & 31;
  const int fq = l >> 5;
  const int swz = (l & 7) ^ ((l >> 3) & 3);
  int pc[4];
#pragma unroll
  for (int s = 0; s < 4; ++s) pc[s] = ((((s << 1) + fq) ^ swz) << 3);
  int aoff[2], boff[2];
#pragma unroll
  for (int i = 0; i < 2; ++i) {
    aoff[i] = (wm * 64 + i * 32 + fr) * 64;
    boff[i] = (wn * 64 + i * 32 + fr) * 64;
  }

  f32x16 acc[2][2] = {};
  const int NT = K >> 6;           // K-tiles (16/32/64 at our call sites)

  // ---- prologue: t0 full (B0-3,A0-3), then t1 (B0-3, A0, A2) ----
#pragma unroll
  for (int j = 0; j < 4; ++j) STB(j, 0, 0);
#pragma unroll
  for (int q = 0; q < 4; ++q) STA(q, 0, 0);
#pragma unroll
  for (int j = 0; j < 4; ++j) STB(j, 1, ABUF);
  STA(0, 1, ABUF); STA(2, 1, ABUF);
  asm volatile("s_waitcnt vmcnt(6)" ::: "memory");   // tile0's 8 landed
  __builtin_amdgcn_s_barrier();

  for (int t = 0; t < NT; ++t) {
    const int bf = t & 1;
    const int aB = bf * ABUF, oaB = (bf ^ 1) * ABUF;
    const bool g1 = (t + 1 < NT), g2 = (t + 2 < NT);
    s8vec b[2][4], a0[4], a1[4];

    // -- WA: read B + A-mf0 (batch1), read-ahead A-mf1 (batch2);
    //        stage A-stripes{1,3}(t+1, other buf) --
#pragma unroll
    for (int s = 0; s < 4; ++s) {
      b[0][s] = *(const s8vec*)&Bs[aB + boff[0] + pc[s]];
      b[1][s] = *(const s8vec*)&Bs[aB + boff[1] + pc[s]];
      a0[s]   = *(const s8vec*)&As[aB + aoff[0] + pc[s]];
    }
    SB0();                         // pin batch boundary: (B,mf0) | (mf1)
#pragma unroll
    for (int s = 0; s < 4; ++s)
      a1[s] = *(const s8vec*)&As[aB + aoff[1] + pc[s]];
    if (g1) { STA(1, t + 1, oaB); STA(3, t + 1, oaB); }
    SB0();
    asm volatile("s_waitcnt lgkmcnt(4)" ::: "memory");   // batch1 done
    SB0();
    __builtin_amdgcn_s_setprio(1);
#pragma unroll
    for (int s = 0; s < 4; ++s)
#pragma unroll
      for (int nf = 0; nf < 2; ++nf)
        acc[0][nf] = __builtin_amdgcn_mfma_f32_32x32x16_bf16(a0[s], b[nf][s], acc[0][nf], 0, 0, 0);
    SB0();
    __builtin_amdgcn_s_setprio(0);
    __builtin_amdgcn_s_barrier();   // all waves past lgkm(4) -> B/A0/A2 restageable

    // -- WB: stage B(t+2)+A{0,2}(t+2) (this buf); MFMA mf1; one fence/tile --
    if (g2) {
#pragma unroll
      for (int j = 0; j < 4; ++j) STB(j, t + 2, aB);
      STA(0, t + 2, aB); STA(2, t + 2, aB);
    }
    SB0();
    asm volatile("s_waitcnt lgkmcnt(0)" ::: "memory");   // batch2 done
    SB0();
    __builtin_amdgcn_s_setprio(1);
#pragma unroll
    for (int s = 0; s < 4; ++s)
#pragma unroll
      for (int nf = 0; nf < 2; ++nf)
        acc[1][nf] = __builtin_amdgcn_mfma_f32_32x32x16_bf16(a1[s], b[nf][s], acc[1][nf], 0, 0, 0);
    SB0();
    __builtin_amdgcn_s_setprio(0);
    if (g2) asm volatile("s_waitcnt vmcnt(6)" ::: "memory");
    else    asm volatile("s_waitcnt vmcnt(0)" ::: "memory");
    __builtin_amdgcn_s_barrier();   // tile t+1 fully resident
  }

  // ---- epilogue.  C/D: col = lane&31, row = (reg&3)+8*(reg>>2)+4*(lane>>5) ----
  float* oF = outF + (size_t)z * bO;
  unsigned short* oB = outB + (size_t)z * bO;
  const float* rs = res + (size_t)z * bR;

  float bcol[2];
  if (EPI >= 2) {
#pragma unroll
    for (int nf = 0; nf < 2; ++nf) bcol[nf] = bias[tileN + wn * 64 + nf * 32 + fr];
  }

#pragma unroll
  for (int mf = 0; mf < 2; ++mf) {
#pragma unroll
    for (int r = 0; r < 16; ++r) {
      const size_t row = tileM + wm * 64 + (mf << 5) + (r & 3) + ((r >> 2) << 3) + (fq << 2);
      const size_t rb = row * (size_t)N;
#pragma unroll
      for (int nf = 0; nf < 2; ++nf) {
        const size_t col = tileN + wn * 64 + (nf << 5) + fr;
        const float v = acc[mf][nf][r];
        if (EPI == 0) {
          oB[rb + col] = f2bf(v * scale);
        } else if (EPI == 1) {
          oF[rb + col] = v + rs[rb + col];
        } else if (EPI == 2) {
          oB[rb + col] = f2bf(fast_gelu(v + bcol[nf]));
        } else {
          oF[rb + col] = v + bcol[nf] + rs[rb + col];
        }
      }
    }
  }
}

// ---------- LayerNorm over rows of 1024 fp32 -> bf16 ----------
__global__ __launch_bounds__(256) void ln_row(
    const float* __restrict__ x, const float* __restrict__ gamma,
    const float* __restrict__ beta, unsigned short* __restrict__ out)
{
  const int row = blockIdx.x;
  const float4* xr = (const float4*)(x + (size_t)row * 1024);
  const int tid = threadIdx.x;
  float4 v = xr[tid];
  float s = v.x + v.y + v.z + v.w;
  float q = v.x * v.x + v.y * v.y + v.z * v.z + v.w * v.w;
#pragma unroll
  for (int off = 32; off > 0; off >>= 1) {
    s += __shfl_down(s, off);
    q += __shfl_down(q, off);
  }
  __shared__ float rs_[4], rq_[4];
  const int w = tid >> 6, l = tid & 63;
  if (l == 0) { rs_[w] = s; rq_[w] = q; }
  __syncthreads();
  s = rs_[0] + rs_[1] + rs_[2] + rs_[3];
  q = rq_[0] + rq_[1] + rq_[2] + rq_[3];
  const float mu = s * (1.0f / 1024.0f);
  const float var = q * (1.0f / 1024.0f) - mu * mu;
  const float rstd = rsqrtf(var + 1e-5f);
  const float4 g = ((const float4*)gamma)[tid];
  const float4 b = ((const float4*)beta)[tid];
  us4 o;
  o.x = f2bf((v.x - mu) * rstd * g.x + b.x);
  o.y = f2bf((v.y - mu) * rstd * g.y + b.y);
  o.z = f2bf((v.z - mu) * rstd * g.z + b.z);
  o.w = f2bf((v.w - mu) * rstd * g.w + b.w);
  ((us4*)(out + (size_t)row * 1024))[tid] = o;
}

// ---------- softmax over rows of 2048 bf16 -> bf16 ----------
__global__ __launch_bounds__(256) void softmax_row(
    const unsigned short* __restrict__ sc, unsigned short* __restrict__ pr)
{
  const int row = blockIdx.x;
  const s8vec* s8 = (const s8vec*)(sc + (size_t)row * 2048);
  const int tid = threadIdx.x;
  s8vec a = s8[tid];                 // 8 bf16
  float x[8];
#pragma unroll
  for (int i = 0; i < 8; ++i) x[i] = bf2f((unsigned short)a[i]);
  float mx = x[0];
#pragma unroll
  for (int i = 1; i < 8; ++i) mx = fmaxf(mx, x[i]);
#pragma unroll
  for (int off = 32; off > 0; off >>= 1) mx = fmaxf(mx, __shfl_down(mx, off));
  __shared__ float red[4];
  const int w = tid >> 6, l = tid & 63;
  if (l == 0) red[w] = mx;
  __syncthreads();
  mx = fmaxf(fmaxf(red[0], red[1]), fmaxf(red[2], red[3]));
  __syncthreads();
  float e[8], s = 0.f;
#pragma unroll
  for (int i = 0; i < 8; ++i) { e[i] = __expf(x[i] - mx); s += e[i]; }
#pragma unroll
  for (int off = 32; off > 0; off >>= 1) s += __shfl_down(s, off);
  if (l == 0) red[w] = s;
  __syncthreads();
  s = red[0] + red[1] + red[2] + red[3];
  const float inv = 1.0f / s;
  s8vec o;
#pragma unroll
  for (int i = 0; i < 8; ++i) o[i] = (short)f2bf(e[i] * inv);
  ((s8vec*)(pr + (size_t)row * 2048))[tid] = o;
}

// ---------- fast 64x64-tile transposes (vectorized; G13) ----------
// f32 in [R][C] -> bf16 out [C][R]
__global__ __launch_bounds__(256) void tconv_f32(
    const float* __restrict__ in, unsigned short* __restrict__ out, int R, int C)
{
  __shared__ float tile[64][65];
  const int tid = threadIdx.x;
  const int c0 = blockIdx.x * 64, r0 = blockIdx.y * 64;
#pragma unroll
  for (int k2 = 0; k2 < 4; ++k2) {
    const int idx = tid + k2 * 256;
    const int row = idx >> 4, c4 = (idx & 15) << 2;
    const float4 v = *(const float4*)&in[(size_t)(r0 + row) * C + c0 + c4];
    tile[row][c4] = v.x; tile[row][c4 + 1] = v.y;
    tile[row][c4 + 2] = v.z; tile[row][c4 + 3] = v.w;
  }
  __syncthreads();
#pragma unroll
  for (int k2 = 0; k2 < 4; ++k2) {
    const int idx = tid + k2 * 256;
    const int cc = idx >> 4, r4 = (idx & 15) << 2;
    us4 o;
#pragma unroll
    for (int j = 0; j < 4; ++j) o[j] = f2bf(tile[r4 + j][cc]);
    *(us4*)&out[(size_t)(c0 + cc) * R + r0 + r4] = o;
  }
}

// bf16 in [R][C] -> bf16 out [C][R], batched
__global__ __launch_bounds__(256) void tconv_bf16(
    const unsigned short* __restrict__ in, unsigned short* __restrict__ out,
    int R, int C, long long bIn, long long bOut)
{
  __shared__ unsigned short tile[64][66];
  const int tid = threadIdx.x;
  const int z = blockIdx.z;
  in += (size_t)z * bIn;
  out += (size_t)z * bOut;
  const int c0 = blockIdx.x * 64, r0 = blockIdx.y * 64;
#pragma unroll
  for (int k2 = 0; k2 < 2; ++k2) {
    const int idx = tid + k2 * 256;
    const int row = idx >> 3, c8 = (idx & 7) << 3;
    const us8 v = *(const us8*)&in[(size_t)(r0 + row) * C + c0 + c8];
#pragma unroll
    for (int j = 0; j < 8; ++j) tile[row][c8 + j] = v[j];
  }
  __syncthreads();
#pragma unroll
  for (int k2 = 0; k2 < 4; ++k2) {
    const int idx = tid + k2 * 256;
    const int cc = idx >> 4, r4 = (idx & 15) << 2;
    us4 o;
#pragma unroll
    for (int j = 0; j < 4; ++j) o[j] = tile[r4 + j][cc];
    *(us4*)&out[(size_t)(c0 + cc) * R + r0 + r4] = o;
  }
}

// ---------- launch ----------
extern "C" void kernel_launch(void* const* d_in, const int* in_sizes, int n_in,
                              void* d_out, int out_size, void* d_ws, size_t ws_size,
                              hipStream_t stream)
{
  (void)in_sizes; (void)n_in; (void)out_size; (void)ws_size;
  const float* src = (const float*)d_in[0];
  const float* g1  = (const float*)d_in[1];
  const float* be1 = (const float*)d_in[2];
  const float* g2  = (const float*)d_in[3];
  const float* be2 = (const float*)d_in[4];
  const float* w1  = (const float*)d_in[5];
  const float* b1  = (const float*)d_in[6];
  const float* w2  = (const float*)d_in[7];
  const float* b2  = (const float*)d_in[8];
  float* out = (float*)d_out;

  // workspace layout (bytes). Peak = 184,549,376.
  char* ws = (char*)d_ws;
  const size_t SZ_NORMX  = (size_t)8192 * 1024 * 2;     // 16 MiB
  const size_t SZ_SCORES = (size_t)4 * 2048 * 2048 * 4; // 64 MiB region (scores bf16 uses half; hbuf uses all)
  const size_t SZ_PROBS  = (size_t)4 * 2048 * 2048 * 2; // 32 MiB
  const size_t SZ_X      = (size_t)8192 * 1024 * 4;     // 32 MiB
  const size_t SZ_W1T    = (size_t)1024 * 4096 * 2;     // 8 MiB

  unsigned short* normx  = (unsigned short*)(ws);
  unsigned short* normxT = (unsigned short*)(ws + SZ_NORMX);
  unsigned short* scores = (unsigned short*)(ws + 2 * SZ_NORMX);
  unsigned short* probs  = (unsigned short*)(ws + 2 * SZ_NORMX + SZ_SCORES);
  float*          xbuf   = (float*)(ws + 2 * SZ_NORMX + SZ_SCORES + SZ_PROBS);
  unsigned short* w1t    = (unsigned short*)(ws + 2 * SZ_NORMX + SZ_SCORES + SZ_PROBS + SZ_X);
  unsigned short* w2t    = (unsigned short*)(ws + 2 * SZ_NORMX + SZ_SCORES + SZ_PROBS + SZ_X + SZ_W1T);
  unsigned short* normx2 = normx;                       // reuse (dead after attn)
  unsigned short* hbuf   = scores;                      // reuse (dead after softmax)

  // weights fp32 -> bf16 transposed (every call; ws is re-poisoned)
  tconv_f32<<<dim3(64, 16), 256, 0, stream>>>(w1, w1t, 1024, 4096);
  tconv_f32<<<dim3(16, 64), 256, 0, stream>>>(w2, w2t, 4096, 1024);

  // LN1
  ln_row<<<8192, 256, 0, stream>>>(src, g1, be1, normx);
  // normx^T per batch (for PV as NT)
  tconv_bf16<<<dim3(16, 32, 4), 256, 0, stream>>>(
      normx, normxT, 2048, 1024, (long long)2048 * 1024, (long long)1024 * 2048);

  // scores = bf16(normx . normx^T / 32)
  gemm128<0><<<dim3(16, 16, 4), 256, 0, stream>>>(
      normx, normx, nullptr, scores, nullptr, nullptr,
      2048, 2048, 1024,
      (long long)2048 * 1024, (long long)2048 * 1024, (long long)2048 * 2048, 0, 0.03125f);

  // softmax rows (bf16 in/out)
  softmax_row<<<8192, 256, 0, stream>>>(scores, probs);

  // x = probs . normx + src
  gemm128<1><<<dim3(8, 16, 4), 256, 0, stream>>>(
      probs, normxT, xbuf, nullptr, nullptr, src,
      2048, 1024, 2048,
      (long long)2048 * 2048, (long long)1024 * 2048, (long long)2048 * 1024,
      (long long)2048 * 1024, 1.0f);

  // LN2
  ln_row<<<8192, 256, 0, stream>>>(xbuf, g2, be2, normx2);

  // h = gelu(normx2 . w1 + b1)
  gemm128<2><<<dim3(32, 64, 1), 256, 0, stream>>>(
      normx2, w1t, nullptr, hbuf, b1, nullptr,
      8192, 4096, 1024, 0, 0, 0, 0, 1.0f);

  // out = h . w2 + b2 + x
  gemm128<3><<<dim3(8, 64, 1), 256, 0, stream>>>(
      hbuf, w2t, out, nullptr, b2, xbuf,
      8192, 1024, 4096, 0, 0, 0, 0, 1.0f);
}